// Round 12
// baseline (500.682 us; speedup 1.0000x reference)
//
#include <hip/hip_runtime.h>

// ---------------------------------------------------------------------------
// DecoderLayer (B=2,S=2048,D=1024,H=16,HD=64,FFN=4096). fp32 I/O, bf16 MFMA.
// R20:
//  - attn_v10 = v9 + VALU offload (VALU 37% > Mfma 24% was the busier pipe):
//    (a) l row-sum via MFMA-ones: l4 = mfma(pf, ones, l4) -> deletes 32
//        v_adds/k-tile AND the shuffle epilogue (D-layout gives l[quad*4+r]
//        in l4[r] directly). Denominator now sums the same bf16-quantized P
//        as PV (consistency bonus).
//    (b) T12 v_cvt_pk_bf16_f32 (inline asm, RNE) replaces 3-op pack2_rz.
// R19: gemm_bt KH param; fc2/Q2 <64,64,KH=2> (half the barrier pairs).
// R17: attn T14 async-stage split (K dbuf + V reg-stage).
// R12: gemm_bt <BM,BN>; fc2/Q2/KV2 BM=64. R11: bare v_exp_f32.
// R10: attn 512 thr. R9: T1 XCD swizzle; T5 setprio.
// R8: swapped QK^T; global_load_lds; XOR-swizzled LDS.
// ---------------------------------------------------------------------------

typedef unsigned short u16;
typedef unsigned int u32;
typedef short v8s __attribute__((ext_vector_type(8)));
typedef float v4f __attribute__((ext_vector_type(4)));

#define LDP 72
#define LOG2E 1.44269504088896340736f

__device__ __forceinline__ float b2f(u16 h) {
    return __uint_as_float(((u32)h) << 16);
}
__device__ __forceinline__ u16 f2b(float f) {          // RNE
    u32 u = __float_as_uint(f);
    u += 0x7fffu + ((u >> 16) & 1u);
    return (u16)(u >> 16);
}
__device__ __forceinline__ void gload16(const void* g, void* l) {
    __builtin_amdgcn_global_load_lds(
        (const __attribute__((address_space(1))) unsigned int*)g,
        (__attribute__((address_space(3))) unsigned int*)l, 16, 0, 0);
}
// bijective XCD chunk swizzle (m204): hardware linear id -> logical tile id
__device__ __forceinline__ int xcd_swz(int orig, int nwg) {
    const int q = nwg >> 3, r = nwg & 7;
    const int xcd = orig & 7, idx = orig >> 3;
    return (xcd < r ? xcd * (q + 1) : r * (q + 1) + (xcd - r) * q) + idx;
}

// ---------------------------------------------------------------------------
// fp32 -> bf16 elementwise. grid n/2048, 256 thr, 8 elems/thr.
// ---------------------------------------------------------------------------
__global__ __launch_bounds__(256) void conv_f2b(
    const float* __restrict__ src, u16* __restrict__ dst)
{
    const size_t i = ((size_t)blockIdx.x * 256 + threadIdx.x) * 8;
    float4 a = *(const float4*)&src[i];
    float4 b = *(const float4*)&src[i + 4];
    ushort4 o0, o1;
    o0.x = f2b(a.x); o0.y = f2b(a.y); o0.z = f2b(a.z); o0.w = f2b(a.w);
    o1.x = f2b(b.x); o1.y = f2b(b.y); o1.z = f2b(b.z); o1.w = f2b(b.w);
    *(ushort4*)&dst[i] = o0;
    *(ushort4*)&dst[i + 4] = o1;
}

// ---------------------------------------------------------------------------
// fp32 src[R][C] -> bf16 dst[C][R].  grid (C/32, R/32), 256 thr.
// ---------------------------------------------------------------------------
__global__ __launch_bounds__(256) void transpose_f2b(
    const float* __restrict__ src, u16* __restrict__ dst, int R, int C)
{
    __shared__ u16 tile[32][33];
    const int t  = threadIdx.x;
    const int tx = t & 31, ty = t >> 5;
    const int r0 = blockIdx.y * 32, c0 = blockIdx.x * 32;
#pragma unroll
    for (int i = 0; i < 32; i += 8)
        tile[ty + i][tx] = f2b(src[(size_t)(r0 + ty + i) * C + c0 + tx]);
    __syncthreads();
#pragma unroll
    for (int i = 0; i < 32; i += 8)
        dst[(size_t)(c0 + ty + i) * R + r0 + tx] = tile[tx][ty + i];
}

// ---------------------------------------------------------------------------
// bias concat (fp32)
// ---------------------------------------------------------------------------
__global__ __launch_bounds__(256) void prep_bias(
    const float* __restrict__ bq, const float* __restrict__ bk, const float* __restrict__ bv,
    const float* __restrict__ cbk, const float* __restrict__ cbv,
    float* __restrict__ sab, float* __restrict__ cakvb)
{
    int i = blockIdx.x * 256 + threadIdx.x;
    if (i < 1024) {
        sab[i]          = bq[i];
        sab[1024 + i]   = bk[i];
        sab[2048 + i]   = bv[i];
        cakvb[i]        = cbk[i];
        cakvb[1024 + i] = cbv[i];
    }
}

// ---------------------------------------------------------------------------
// GEMM: C[M,N] = A[M,K]*Bt[N,K]^T + bias[N]; optional relu; cols<qcols scaled
// by qscale; cols>=vtcol0 (if >=0) written transposed to vt[bh][hd][2048].
// A is bf16. BM/BN/KH template. grid (N/BN, M/BM), 256 thr, 4 waves 2x2.
// KH = BK64 sub-tiles staged per barrier pair (halves barrier count at KH=2).
// ---------------------------------------------------------------------------
template <int BM, int BN, int KH>
__global__ __launch_bounds__(256) void gemm_bt(
    const u16* __restrict__ A, const u16* __restrict__ Bt,
    const float* __restrict__ bias, u16* __restrict__ C,
    int M, int N, int K, int relu, int qcols, float qscale,
    u16* __restrict__ vt, int vtcol0)
{
    constexpr int MI = BM / 32;   // m-frags per wave (wave covers BM/2 rows)
    constexpr int NI = BN / 32;   // n-frags per wave (wave covers BN/2 cols)
    __shared__ __align__(16) u16 Al[KH][BM * 64];
    __shared__ __align__(16) u16 Bl[KH][BN * 64];
    const int tid  = threadIdx.x;
    const int wave = tid >> 6, lane = tid & 63;
    const int quad = lane >> 4, tl = lane & 15;
    // T1: XCD-aware bijective remap of the block id (perf-only; bijection)
    const int nwg  = gridDim.x * gridDim.y;
    const int wgid = xcd_swz(blockIdx.y * gridDim.x + blockIdx.x, nwg);
    const int bx   = wgid % gridDim.x, by = wgid / gridDim.x;
    const int bm0 = by * BM, bn0 = bx * BN;
    const int wm = (wave >> 1) * (BM / 2), wn = (wave & 1) * (BN / 2);
    const int srow = lane >> 3;
    const int scol = (((lane & 7) ^ srow) << 3);

    const v4f z4 = {0.f, 0.f, 0.f, 0.f};
    v4f acc[MI][NI];
#pragma unroll
    for (int i = 0; i < MI; ++i)
#pragma unroll
        for (int j = 0; j < NI; ++j) acc[i][j] = z4;

    for (int kt = 0; kt < K; kt += 64 * KH) {
#pragma unroll
        for (int h = 0; h < KH; ++h) {
#pragma unroll
            for (int i = 0; i < MI; ++i) {
                const int c = wave * MI + i;
                const int row = c * 8 + srow;
                gload16(&A[(size_t)(bm0 + row) * K + kt + h * 64 + scol], &Al[h][c * 512]);
            }
#pragma unroll
            for (int i = 0; i < NI; ++i) {
                const int c = wave * NI + i;
                const int row = c * 8 + srow;
                gload16(&Bt[(size_t)(bn0 + row) * K + kt + h * 64 + scol], &Bl[h][c * 512]);
            }
        }
        __syncthreads();
#pragma unroll
        for (int h = 0; h < KH; ++h) {
#pragma unroll
            for (int kk = 0; kk < 2; ++kk) {
                const int pc = ((kk * 4 + quad) ^ (tl & 7)) << 3;
                v8s af[MI], bf[NI];
#pragma unroll
                for (int i = 0; i < MI; ++i) af[i] = *(const v8s*)&Al[h][(wm + i * 16 + tl) * 64 + pc];
#pragma unroll
                for (int i = 0; i < NI; ++i) bf[i] = *(const v8s*)&Bl[h][(wn + i * 16 + tl) * 64 + pc];
#pragma unroll
                for (int mi = 0; mi < MI; ++mi)
#pragma unroll
                    for (int ni = 0; ni < NI; ++ni)
                        acc[mi][ni] = __builtin_amdgcn_mfma_f32_16x16x32_bf16(
                            af[mi], bf[ni], acc[mi][ni], 0, 0, 0);
            }
        }
        __syncthreads();
    }
#pragma unroll
    for (int ni = 0; ni < NI; ++ni) {
        int col = bn0 + wn + ni * 16 + tl;
        float bv = bias[col];
        if (vtcol0 >= 0 && col >= vtcol0) {
            int cv = col - vtcol0;
            int h = cv >> 6, hd = cv & 63;
#pragma unroll
            for (int mi = 0; mi < MI; ++mi) {
                int row0 = bm0 + wm + mi * 16 + (quad << 2);
                int bb = row0 >> 11, s = row0 & 2047;
                ushort4 pk;
                pk.x = f2b(acc[mi][ni][0] + bv);
                pk.y = f2b(acc[mi][ni][1] + bv);
                pk.z = f2b(acc[mi][ni][2] + bv);
                pk.w = f2b(acc[mi][ni][3] + bv);
                *(ushort4*)&vt[((size_t)(bb * 16 + h) * 64 + hd) * 2048 + s] = pk;
            }
        } else {
            float sc = (col < qcols) ? qscale : 1.0f;
#pragma unroll
            for (int mi = 0; mi < MI; ++mi) {
                int row0 = bm0 + wm + mi * 16 + (quad << 2);
#pragma unroll
                for (int r = 0; r < 4; ++r) {
                    float vv = acc[mi][ni][r] + bv;
                    if (relu) vv = fmaxf(vv, 0.f);
                    vv *= sc;
                    C[(size_t)(row0 + r) * N + col] = f2b(vv);
                }
            }
        }
    }
}

// ---------------------------------------------------------------------------
// Flash attention v10: v9 + MFMA-ones l row-sum + cvt_pk bf16 pack.
// 8 waves x 16 q-rows (512 thr). K double-buffered in LDS (async prefetch),
// V(t+1) reg-staged under compute. l[q] accumulated on the MATRIX pipe:
// l4 = mfma(pf, ones, l4) -> l4[r] = l[quad*4+r] at every lane, no shuffles.
// grid (S/128, B*H), 512 thr.  T1 swizzle: whole heads per XCD.
// ---------------------------------------------------------------------------
__global__ __launch_bounds__(512) void attn_v10(
    const u16* __restrict__ Q, int qs, const u16* __restrict__ Kp, int ks,
    const u16* __restrict__ Vt, u16* __restrict__ O, int os, int Sk)
{
    __shared__ __align__(16) u16 Kl[2][128 * 64]; // [sk][hd]  32 KB dbuf
    __shared__ __align__(16) u16 Vtl[64 * 128];   // [hd][sk]  16 KB
    __shared__ __align__(16) u16 Pl[8][16 * LDP]; //           18 KB

    const int tid  = threadIdx.x;
    const int wave = tid >> 6, lane = tid & 63;
    const int quad = lane >> 4, tl = lane & 15;
    // T1: XCD-aware bijective remap (contiguous heads per XCD)
    const int nwg  = gridDim.x * gridDim.y;
    const int wgid = xcd_swz(blockIdx.y * gridDim.x + blockIdx.x, nwg);
    const int bx   = wgid % gridDim.x, by = wgid / gridDim.x;
    const int b = by >> 4, h = by & 15;
    const int srow = lane >> 3;
    const int scolK = (((lane & 7) ^ srow) << 3);
    const int vri = lane >> 4, vj = lane & 15;   // Vt staging roles

    const u16* qb  = Q  + (size_t)(b * 2048) * qs + h * 64;
    const u16* kb  = Kp + (size_t)(b * 2048) * ks + h * 64;
    const u16* vtb = Vt + (size_t)by * 64 * 2048;
    u16*       ob  = O  + (size_t)(b * 2048) * os + h * 64;
    const int qr0 = bx * 128 + wave * 16;        // 16 q-rows per wave

    v8s qf[2];
#pragma unroll
    for (int kk = 0; kk < 2; ++kk)
        qf[kk] = *(const v8s*)&qb[(size_t)(qr0 + tl) * qs + kk * 32 + quad * 8];

    const v4f z4 = {0.f, 0.f, 0.f, 0.f};
    v4f oacc[4] = {z4, z4, z4, z4};
    v4f l4 = z4;                                 // l[q] accumulated via MFMA
    v8s ones;
#pragma unroll
    for (int i = 0; i < 8; ++i) ones[i] = (short)0x3F80;  // bf16 1.0
    u16* Pw = &Pl[wave][0];

    const int pc0 = (quad ^ (tl & 7)) << 3;
    const int pc1 = ((4 + quad) ^ (tl & 7)) << 3;

    // prologue: stage K(0) -> Kl[0], V(0) -> Vtl
#pragma unroll
    for (int i = 0; i < 2; ++i) {
        const int c = wave * 2 + i;
        gload16(&kb[(size_t)(c * 8 + srow) * ks + scolK], &Kl[0][c * 512]);
    }
#pragma unroll
    for (int i = 0; i < 2; ++i) {
        const int c = wave * 2 + i;
        const int vr = c * 4 + vri;
        const int g = (vj & 8) | ((vj & 7) ^ (vr & 7));
        gload16(&vtb[(size_t)vr * 2048 + (g << 3)], &Vtl[c * 512]);
    }
    __syncthreads();

    int cur = 0;
    for (int kt = 0; kt < Sk; kt += 128) {
        const int more = (kt + 128 < Sk) ? 1 : 0;
        v8s vp0, vp1;
        if (more) {
            // reg-load V(t+1) early: latency hides under this iteration's
            // compute; values land in Vtl after barrier#1.
            {
                const int c = wave * 2 + 0;
                const int vr = c * 4 + vri;
                const int g = (vj & 8) | ((vj & 7) ^ (vr & 7));
                vp0 = *(const v8s*)&vtb[(size_t)vr * 2048 + kt + 128 + (g << 3)];
            }
            {
                const int c = wave * 2 + 1;
                const int vr = c * 4 + vri;
                const int g = (vj & 8) | ((vj & 7) ^ (vr & 7));
                vp1 = *(const v8s*)&vtb[(size_t)vr * 2048 + kt + 128 + (g << 3)];
            }
            // issue K(t+1) -> Kl[cur^1]: async, completes under compute.
#pragma unroll
            for (int i = 0; i < 2; ++i) {
                const int c = wave * 2 + i;
                const int row = c * 8 + srow;
                gload16(&kb[(size_t)(kt + 128 + row) * ks + scolK], &Kl[cur ^ 1][c * 512]);
            }
        }
        const u16* Kc = &Kl[cur][0];

#pragma unroll
        for (int hf = 0; hf < 2; ++hf) {
            // S^T = K*Q^T for this 64-sk half (lane: sk=quad*4+r, q=tl)
#pragma unroll
            for (int nt = 0; nt < 4; ++nt) {
                const int krow = ((hf * 4 + nt) * 16 + tl) * 64;
                v8s k0 = *(const v8s*)&Kc[krow + pc0];
                v8s k1 = *(const v8s*)&Kc[krow + pc1];
                v4f a = z4;
                a = __builtin_amdgcn_mfma_f32_16x16x32_bf16(k0, qf[0], a, 0, 0, 0);
                a = __builtin_amdgcn_mfma_f32_16x16x32_bf16(k1, qf[1], a, 0, 0, 0);
                // bare v_exp_f32: scores pre-scaled by 0.125*log2e, bounded.
                float p0 = __builtin_amdgcn_exp2f(a[0]);
                float p1 = __builtin_amdgcn_exp2f(a[1]);
                float p2 = __builtin_amdgcn_exp2f(a[2]);
                float p3 = __builtin_amdgcn_exp2f(a[3]);
                // T12: single-inst f32x2 -> bf16x2 pack (RNE)
                u32 pk0, pk1;
                asm("v_cvt_pk_bf16_f32 %0, %1, %2" : "=v"(pk0) : "v"(p0), "v"(p1));
                asm("v_cvt_pk_bf16_f32 %0, %1, %2" : "=v"(pk1) : "v"(p2), "v"(p3));
                uint2 pk; pk.x = pk0; pk.y = pk1;
                // P[q][sk]: row = tl, cols nt*16+quad*4 .. +3
                *(uint2*)&Pw[tl * LDP + nt * 16 + quad * 4] = pk;
            }
            asm volatile("" ::: "memory");   // same-wave DS ordering fence

            v8s pf0 = *(const v8s*)&Pw[tl * LDP + quad * 8];
            v8s pf1 = *(const v8s*)&Pw[tl * LDP + 32 + quad * 8];
            const int pv0 = ((hf * 8) | (quad ^ (tl & 7))) << 3;
            const int pv1 = ((hf * 8) | ((4 + quad) ^ (tl & 7))) << 3;
            // T5: pure-MFMA cluster — hint scheduler to keep matrix pipe fed
            __builtin_amdgcn_s_setprio(1);
            // l row-sum on the matrix pipe: B = ones (layout-independent)
            l4 = __builtin_amdgcn_mfma_f32_16x16x32_bf16(pf0, ones, l4, 0, 0, 0);
            l4 = __builtin_amdgcn_mfma_f32_16x16x32_bf16(pf1, ones, l4, 0, 0, 0);
#pragma unroll
            for (int d = 0; d < 4; ++d) {
                const int vbase = (d * 16 + tl) * 128;
                v8s v0 = *(const v8s*)&Vtl[vbase + pv0];
                v8s v1 = *(const v8s*)&Vtl[vbase + pv1];
                oacc[d] = __builtin_amdgcn_mfma_f32_16x16x32_bf16(pf0, v0, oacc[d], 0, 0, 0);
                oacc[d] = __builtin_amdgcn_mfma_f32_16x16x32_bf16(pf1, v1, oacc[d], 0, 0, 0);
            }
            __builtin_amdgcn_s_setprio(0);
            asm volatile("" ::: "memory");   // P region reused next half
        }

        __syncthreads();   // all waves done reading Vtl; prefetches retired
        if (more) {
            // write V(t+1) into Vtl at the gload-linear offsets (same layout)
            *(v8s*)&Vtl[(wave * 2 + 0) * 512 + lane * 8] = vp0;
            *(v8s*)&Vtl[(wave * 2 + 1) * 512 + lane * 8] = vp1;
        }
        __syncthreads();   // Vtl(t+1) visible to all waves
        cur ^= 1;
    }

    // l4[r] = l[q = quad*4 + r] (D-layout row = quad*4+reg, same for all tl)
#pragma unroll
    for (int r = 0; r < 4; ++r) {
        float inv = 1.0f / l4[r];
#pragma unroll
        for (int d = 0; d < 4; ++d)
            ob[(size_t)(qr0 + quad * 4 + r) * os + d * 16 + tl] =
                f2b(oacc[d][r] * inv);
    }
}

// ---------------------------------------------------------------------------
// out = LayerNorm(x + h) * g + b   over D=1024. grid 4096, 256 thr.
// ---------------------------------------------------------------------------
template <int XF32, int OF32>
__global__ __launch_bounds__(256) void add_ln(
    const void* __restrict__ Xv, const u16* __restrict__ Hh,
    const float* __restrict__ G, const float* __restrict__ Bb,
    void* __restrict__ Outv)
{
    const int row = blockIdx.x, t = threadIdx.x;
    float v0, v1, v2, v3;
    {
        ushort4 hv = *(const ushort4*)&Hh[(size_t)row * 1024 + t * 4];
        if (XF32) {
            const float* xr = (const float*)Xv + (size_t)row * 1024;
            float4 xv = *(const float4*)&xr[t * 4];
            v0 = xv.x + b2f(hv.x); v1 = xv.y + b2f(hv.y);
            v2 = xv.z + b2f(hv.z); v3 = xv.w + b2f(hv.w);
        } else {
            const u16* xr = (const u16*)Xv + (size_t)row * 1024;
            ushort4 xv = *(const ushort4*)&xr[t * 4];
            v0 = b2f(xv.x) + b2f(hv.x); v1 = b2f(xv.y) + b2f(hv.y);
            v2 = b2f(xv.z) + b2f(hv.z); v3 = b2f(xv.w) + b2f(hv.w);
        }
    }

    float s1 = v0 + v1 + v2 + v3;
    float s2 = v0 * v0 + v1 * v1 + v2 * v2 + v3 * v3;
#pragma unroll
    for (int o = 1; o < 64; o <<= 1) {
        s1 += __shfl_xor(s1, o);
        s2 += __shfl_xor(s2, o);
    }
    __shared__ float red[8];
    const int wave = t >> 6, lane = t & 63;
    if (lane == 0) { red[wave] = s1; red[4 + wave] = s2; }
    __syncthreads();
    s1 = red[0] + red[1] + red[2] + red[3];
    s2 = red[4] + red[5] + red[6] + red[7];

    const float mu = s1 * (1.f / 1024.f);
    float var = s2 * (1.f / 1024.f) - mu * mu;
    var = fmaxf(var, 0.f);
    const float rs = rsqrtf(var + 1e-5f);

    float4 gv = *(const float4*)&G[t * 4];
    float4 bv = *(const float4*)&Bb[t * 4];
    float o0 = (v0 - mu) * rs * gv.x + bv.x;
    float o1 = (v1 - mu) * rs * gv.y + bv.y;
    float o2 = (v2 - mu) * rs * gv.z + bv.z;
    float o3 = (v3 - mu) * rs * gv.w + bv.w;

    if (OF32) {
        float4 ov = {o0, o1, o2, o3};
        *(float4*)&((float*)Outv)[(size_t)row * 1024 + t * 4] = ov;
    } else {
        ushort4 ov;
        ov.x = f2b(o0); ov.y = f2b(o1); ov.z = f2b(o2); ov.w = f2b(o3);
        *(ushort4*)&((u16*)Outv)[(size_t)row * 1024 + t * 4] = ov;
    }
}

// ---------------------------------------------------------------------------
extern "C" void kernel_launch(void* const* d_in, const int* in_sizes, int n_in,
                              void* d_out, int out_size, void* d_ws, size_t ws_size,
                              hipStream_t stream) {
    const float* x0  = (const float*)d_in[0];
    const float* enc = (const float*)d_in[1];

    char* wsb = (char*)d_ws;
    const size_t MB = 1024u * 1024u;
    // weights region [0,12MB) — dead after projection GEMMs, reused by FFN
    u16*   wt_sa   = (u16*)(wsb);             // [3072][1024]  0-6 MB
    u16*   wt_caq  = (u16*)(wsb + 6  * MB);   // [1024][1024]  6-8 MB
    u16*   wt_cakv = (u16*)(wsb + 8  * MB);   // [2048][1024]  8-12 MB
    float* sab     = (float*)(wsb + 12 * MB);
    float* cakvb   = (float*)(wsb + 12 * MB + 16384);
    char*  arena   = wsb + 12 * MB + 32768;   // 48 MB arena
    // attention phase
    u16* QKV    = (u16*)(arena);            // [4096][3072] 0-24
    u16* hbuf   = (u16*)(arena + 24 * MB);  // [4096][1024] 24-32 (attn outs)
    u16* x0b    = (u16*)(arena + 24 * MB);  // bf16(x0) — dead once attn1 runs
    u16* encb   = (u16*)(arena + 24 * MB);  // bf16(enc) — lives ln1..attn2
    u16* x1     = (u16*)(arena + 32 * MB);  // [4096][1024] 32-40
    u16* Vt     = (u16*)(arena + 40 * MB);  // [32][64][2048] 40-48
    u16* Q2     = (u16*)(arena);            // 0-8   (reuses QKV)
    u16* KV2    = (u16*)(arena + 8  * MB);  // 8-24  (reuses QKV)
    // FFN phase
    u16* x2     = (u16*)(arena);            // 0-8
    u16* wt_fc1 = (u16*)(wsb);              // ws 0-8 (over proj weights)
    u16* wt_fc2 = (u16*)(arena + 8  * MB);  // 8-16  (dead KV2)
    u16* tbuf   = (u16*)(arena + 16 * MB);  // [4096][4096] 16-48
    u16* h3     = (u16*)(wsb);              // ws 0-8 (wt_fc1 dead after fc1)

    const float QSC = 0.125f * LOG2E;

    prep_bias<<<4, 256, 0, stream>>>(
        (const float*)d_in[3], (const float*)d_in[5], (const float*)d_in[7],
        (const float*)d_in[13], (const float*)d_in[15], sab, cakvb);

    transpose_f2b<<<dim3(32, 32), 256, 0, stream>>>((const float*)d_in[2],  wt_sa,               1024, 1024);
    transpose_f2b<<<dim3(32, 32), 256, 0, stream>>>((const float*)d_in[4],  wt_sa + 1024*1024,   1024, 1024);
    transpose_f2b<<<dim3(32, 32), 256, 0, stream>>>((const float*)d_in[6],  wt_sa + 2*1024*1024, 1024, 1024);
    transpose_f2b<<<dim3(32, 32), 256, 0, stream>>>((const float*)d_in[10], wt_caq,              1024, 1024);
    transpose_f2b<<<dim3(32, 32), 256, 0, stream>>>((const float*)d_in[12], wt_cakv,             1024, 1024);
    transpose_f2b<<<dim3(32, 32), 256, 0, stream>>>((const float*)d_in[14], wt_cakv + 1024*1024, 1024, 1024);

    // --- self-attention block ---
    conv_f2b<<<2048, 256, 0, stream>>>(x0, x0b);
    gemm_bt<128, 128, 1><<<dim3(24, 32), 256, 0, stream>>>(
        x0b, wt_sa, sab, QKV, 4096, 3072, 1024, 0, 1024, QSC, Vt, 2048);
    attn_v10<<<dim3(16, 32), 512, 0, stream>>>(QKV, 3072, QKV + 1024, 3072, Vt, hbuf, 1024, 2048);
    add_ln<1, 0><<<4096, 256, 0, stream>>>(x0, hbuf, (const float*)d_in[8], (const float*)d_in[9], x1);

    // --- cross-attention block ---
    conv_f2b<<<2048, 256, 0, stream>>>(enc, encb);
    gemm_bt<64, 64, 2><<<dim3(16, 64), 256, 0, stream>>>(
        x1, wt_caq, (const float*)d_in[11], Q2, 4096, 1024, 1024, 0, 1024, QSC, (u16*)nullptr, -1);
    gemm_bt<64, 128, 1><<<dim3(16, 64), 256, 0, stream>>>(
        encb, wt_cakv, cakvb, KV2, 4096, 2048, 1024, 0, 0, 1.0f, Vt, 1024);
    attn_v10<<<dim3(16, 32), 512, 0, stream>>>(Q2, 1024, KV2, 2048, Vt, hbuf, 1024, 2048);
    add_ln<0, 0><<<4096, 256, 0, stream>>>(x1, hbuf, (const float*)d_in[16], (const float*)d_in[17], x2);

    // --- FFN block ---
    transpose_f2b<<<dim3(128, 32), 256, 0, stream>>>((const float*)d_in[18], wt_fc1, 1024, 4096);
    transpose_f2b<<<dim3(32, 128), 256, 0, stream>>>((const float*)d_in[20], wt_fc2, 4096, 1024);
    gemm_bt<128, 128, 1><<<dim3(32, 32), 256, 0, stream>>>(
        x2, wt_fc1, (const float*)d_in[19], tbuf, 4096, 4096, 1024, 1, 0, 1.0f, (u16*)nullptr, -1);
    gemm_bt<64, 64, 2><<<dim3(16, 64), 256, 0, stream>>>(
        tbuf, wt_fc2, (const float*)d_in[21], h3, 4096, 1024, 4096, 0, 0, 1.0f, (u16*)nullptr, -1);
    add_ln<0, 1><<<4096, 256, 0, stream>>>(x2, h3, (const float*)d_in[22], (const float*)d_in[23], d_out);
}

// Round 13
// 455.490 us; speedup vs baseline: 1.0992x; 1.0992x over previous
//
#include <hip/hip_runtime.h>

// ---------------------------------------------------------------------------
// DecoderLayer (B=2,S=2048,D=1024,H=16,HD=64,FFN=4096). fp32 I/O, bf16 MFMA.
// R21:
//  - Dispatch fusion: 21 -> 13 dispatches. prep_all = prep_bias + 6 proj
//    weight transposes + conv(x0) in ONE kernel (block-range switch; all
//    writes disjoint). prep_fc = both FFN transposes. conv(enc) stays in
//    place (encb aliases x0b/hbuf at arena+24MB -> cannot hoist).
//  - attn_v10 kept (R20 confirmed: VALU 37->28, Mfma 24->26).
// R20: attn MFMA-ones l-rowsum + cvt_pk pack. R19: gemm KH; fc2/Q2 KH=2.
// R17: attn T14 async-stage split. R12: gemm <BM,BN>; BM=64 for fc2/Q2/KV2.
// R11: bare v_exp_f32. R10: attn 512 thr. R9: T1 XCD swizzle + T5 setprio.
// R8: swapped QK^T; global_load_lds; XOR-swizzled LDS.
// ---------------------------------------------------------------------------

typedef unsigned short u16;
typedef unsigned int u32;
typedef short v8s __attribute__((ext_vector_type(8)));
typedef float v4f __attribute__((ext_vector_type(4)));

#define LDP 72
#define LOG2E 1.44269504088896340736f

__device__ __forceinline__ float b2f(u16 h) {
    return __uint_as_float(((u32)h) << 16);
}
__device__ __forceinline__ u16 f2b(float f) {          // RNE
    u32 u = __float_as_uint(f);
    u += 0x7fffu + ((u >> 16) & 1u);
    return (u16)(u >> 16);
}
__device__ __forceinline__ void gload16(const void* g, void* l) {
    __builtin_amdgcn_global_load_lds(
        (const __attribute__((address_space(1))) unsigned int*)g,
        (__attribute__((address_space(3))) unsigned int*)l, 16, 0, 0);
}
// bijective XCD chunk swizzle (m204): hardware linear id -> logical tile id
__device__ __forceinline__ int xcd_swz(int orig, int nwg) {
    const int q = nwg >> 3, r = nwg & 7;
    const int xcd = orig & 7, idx = orig >> 3;
    return (xcd < r ? xcd * (q + 1) : r * (q + 1) + (xcd - r) * q) + idx;
}

// ---------------------------------------------------------------------------
// fp32 -> bf16 elementwise. grid n/2048, 256 thr, 8 elems/thr.
// ---------------------------------------------------------------------------
__global__ __launch_bounds__(256) void conv_f2b(
    const float* __restrict__ src, u16* __restrict__ dst)
{
    const size_t i = ((size_t)blockIdx.x * 256 + threadIdx.x) * 8;
    float4 a = *(const float4*)&src[i];
    float4 b = *(const float4*)&src[i + 4];
    ushort4 o0, o1;
    o0.x = f2b(a.x); o0.y = f2b(a.y); o0.z = f2b(a.z); o0.w = f2b(a.w);
    o1.x = f2b(b.x); o1.y = f2b(b.y); o1.z = f2b(b.z); o1.w = f2b(b.w);
    *(ushort4*)&dst[i] = o0;
    *(ushort4*)&dst[i + 4] = o1;
}

// ---------------------------------------------------------------------------
// prep_all: fused weight/bias/x0 preparation (11 -> 1 dispatch).
// blocks [0,4): bias concat; [4,2052): conv x0 -> x0b (bf16);
// [2052,8196): 6x transpose_f2b 1024x1024 (proj weights).
// All outputs disjoint; no inter-part ordering needed.
// ---------------------------------------------------------------------------
__global__ __launch_bounds__(256) void prep_all(
    const float* __restrict__ bq, const float* __restrict__ bk,
    const float* __restrict__ bv, const float* __restrict__ cbk,
    const float* __restrict__ cbv, float* __restrict__ sab,
    float* __restrict__ cakvb,
    const float* __restrict__ x0, u16* __restrict__ x0b,
    const float* __restrict__ w0, const float* __restrict__ w1,
    const float* __restrict__ w2, const float* __restrict__ w3,
    const float* __restrict__ w4, const float* __restrict__ w5,
    u16* __restrict__ wt_sa, u16* __restrict__ wt_caq,
    u16* __restrict__ wt_cakv)
{
    __shared__ u16 tile[32][33];
    const int bid = blockIdx.x, t = threadIdx.x;
    if (bid < 4) {
        int i = bid * 256 + t;
        if (i < 1024) {
            sab[i]          = bq[i];
            sab[1024 + i]   = bk[i];
            sab[2048 + i]   = bv[i];
            cakvb[i]        = cbk[i];
            cakvb[1024 + i] = cbv[i];
        }
        return;
    }
    if (bid < 4 + 2048) {
        const size_t i = ((size_t)(bid - 4) * 256 + t) * 8;
        float4 a = *(const float4*)&x0[i];
        float4 b = *(const float4*)&x0[i + 4];
        ushort4 o0, o1;
        o0.x = f2b(a.x); o0.y = f2b(a.y); o0.z = f2b(a.z); o0.w = f2b(a.w);
        o1.x = f2b(b.x); o1.y = f2b(b.y); o1.z = f2b(b.z); o1.w = f2b(b.w);
        *(ushort4*)&x0b[i] = o0;
        *(ushort4*)&x0b[i + 4] = o1;
        return;
    }
    // 6 transposes of 1024x1024 (grid 32x32 each, linearized)
    const int tb = bid - 2052;
    const int which = tb >> 10, c = tb & 1023;
    const float* src; u16* dst;
    switch (which) {
        case 0:  src = w0; dst = wt_sa;               break;
        case 1:  src = w1; dst = wt_sa + 1024*1024;   break;
        case 2:  src = w2; dst = wt_sa + 2*1024*1024; break;
        case 3:  src = w3; dst = wt_caq;              break;
        case 4:  src = w4; dst = wt_cakv;             break;
        default: src = w5; dst = wt_cakv + 1024*1024; break;
    }
    const int bx = c & 31, by = c >> 5;
    const int tx = t & 31, ty = t >> 5;
    const int r0 = by * 32, c0 = bx * 32;
#pragma unroll
    for (int i = 0; i < 32; i += 8)
        tile[ty + i][tx] = f2b(src[(size_t)(r0 + ty + i) * 1024 + c0 + tx]);
    __syncthreads();
#pragma unroll
    for (int i = 0; i < 32; i += 8)
        dst[(size_t)(c0 + ty + i) * 1024 + r0 + tx] = tile[tx][ty + i];
}

// ---------------------------------------------------------------------------
// prep_fc: fused FFN weight transposes (2 -> 1 dispatch).
// blocks [0,4096): fc1 w (1024x4096 -> 4096x1024);
// blocks [4096,8192): fc2 w (4096x1024 -> 1024x4096).
// ---------------------------------------------------------------------------
__global__ __launch_bounds__(256) void prep_fc(
    const float* __restrict__ wf1, const float* __restrict__ wf2,
    u16* __restrict__ wt_fc1, u16* __restrict__ wt_fc2)
{
    __shared__ u16 tile[32][33];
    int bid = blockIdx.x;
    const float* src; u16* dst; int R, C, bx, by;
    if (bid < 4096) { src = wf1; dst = wt_fc1; R = 1024; C = 4096; bx = bid & 127; by = bid >> 7; }
    else { bid -= 4096; src = wf2; dst = wt_fc2; R = 4096; C = 1024; bx = bid & 31; by = bid >> 5; }
    const int t = threadIdx.x;
    const int tx = t & 31, ty = t >> 5;
    const int r0 = by * 32, c0 = bx * 32;
#pragma unroll
    for (int i = 0; i < 32; i += 8)
        tile[ty + i][tx] = f2b(src[(size_t)(r0 + ty + i) * C + c0 + tx]);
    __syncthreads();
#pragma unroll
    for (int i = 0; i < 32; i += 8)
        dst[(size_t)(c0 + ty + i) * R + r0 + tx] = tile[tx][ty + i];
}

// ---------------------------------------------------------------------------
// GEMM: C[M,N] = A[M,K]*Bt[N,K]^T + bias[N]; optional relu; cols<qcols scaled
// by qscale; cols>=vtcol0 (if >=0) written transposed to vt[bh][hd][2048].
// A is bf16. BM/BN/KH template. grid (N/BN, M/BM), 256 thr, 4 waves 2x2.
// KH = BK64 sub-tiles staged per barrier pair (halves barrier count at KH=2).
// ---------------------------------------------------------------------------
template <int BM, int BN, int KH>
__global__ __launch_bounds__(256) void gemm_bt(
    const u16* __restrict__ A, const u16* __restrict__ Bt,
    const float* __restrict__ bias, u16* __restrict__ C,
    int M, int N, int K, int relu, int qcols, float qscale,
    u16* __restrict__ vt, int vtcol0)
{
    constexpr int MI = BM / 32;   // m-frags per wave (wave covers BM/2 rows)
    constexpr int NI = BN / 32;   // n-frags per wave (wave covers BN/2 cols)
    __shared__ __align__(16) u16 Al[KH][BM * 64];
    __shared__ __align__(16) u16 Bl[KH][BN * 64];
    const int tid  = threadIdx.x;
    const int wave = tid >> 6, lane = tid & 63;
    const int quad = lane >> 4, tl = lane & 15;
    // T1: XCD-aware bijective remap of the block id (perf-only; bijection)
    const int nwg  = gridDim.x * gridDim.y;
    const int wgid = xcd_swz(blockIdx.y * gridDim.x + blockIdx.x, nwg);
    const int bx   = wgid % gridDim.x, by = wgid / gridDim.x;
    const int bm0 = by * BM, bn0 = bx * BN;
    const int wm = (wave >> 1) * (BM / 2), wn = (wave & 1) * (BN / 2);
    const int srow = lane >> 3;
    const int scol = (((lane & 7) ^ srow) << 3);

    const v4f z4 = {0.f, 0.f, 0.f, 0.f};
    v4f acc[MI][NI];
#pragma unroll
    for (int i = 0; i < MI; ++i)
#pragma unroll
        for (int j = 0; j < NI; ++j) acc[i][j] = z4;

    for (int kt = 0; kt < K; kt += 64 * KH) {
#pragma unroll
        for (int h = 0; h < KH; ++h) {
#pragma unroll
            for (int i = 0; i < MI; ++i) {
                const int c = wave * MI + i;
                const int row = c * 8 + srow;
                gload16(&A[(size_t)(bm0 + row) * K + kt + h * 64 + scol], &Al[h][c * 512]);
            }
#pragma unroll
            for (int i = 0; i < NI; ++i) {
                const int c = wave * NI + i;
                const int row = c * 8 + srow;
                gload16(&Bt[(size_t)(bn0 + row) * K + kt + h * 64 + scol], &Bl[h][c * 512]);
            }
        }
        __syncthreads();
#pragma unroll
        for (int h = 0; h < KH; ++h) {
#pragma unroll
            for (int kk = 0; kk < 2; ++kk) {
                const int pc = ((kk * 4 + quad) ^ (tl & 7)) << 3;
                v8s af[MI], bf[NI];
#pragma unroll
                for (int i = 0; i < MI; ++i) af[i] = *(const v8s*)&Al[h][(wm + i * 16 + tl) * 64 + pc];
#pragma unroll
                for (int i = 0; i < NI; ++i) bf[i] = *(const v8s*)&Bl[h][(wn + i * 16 + tl) * 64 + pc];
#pragma unroll
                for (int mi = 0; mi < MI; ++mi)
#pragma unroll
                    for (int ni = 0; ni < NI; ++ni)
                        acc[mi][ni] = __builtin_amdgcn_mfma_f32_16x16x32_bf16(
                            af[mi], bf[ni], acc[mi][ni], 0, 0, 0);
            }
        }
        __syncthreads();
    }
#pragma unroll
    for (int ni = 0; ni < NI; ++ni) {
        int col = bn0 + wn + ni * 16 + tl;
        float bv = bias[col];
        if (vtcol0 >= 0 && col >= vtcol0) {
            int cv = col - vtcol0;
            int h = cv >> 6, hd = cv & 63;
#pragma unroll
            for (int mi = 0; mi < MI; ++mi) {
                int row0 = bm0 + wm + mi * 16 + (quad << 2);
                int bb = row0 >> 11, s = row0 & 2047;
                ushort4 pk;
                pk.x = f2b(acc[mi][ni][0] + bv);
                pk.y = f2b(acc[mi][ni][1] + bv);
                pk.z = f2b(acc[mi][ni][2] + bv);
                pk.w = f2b(acc[mi][ni][3] + bv);
                *(ushort4*)&vt[((size_t)(bb * 16 + h) * 64 + hd) * 2048 + s] = pk;
            }
        } else {
            float sc = (col < qcols) ? qscale : 1.0f;
#pragma unroll
            for (int mi = 0; mi < MI; ++mi) {
                int row0 = bm0 + wm + mi * 16 + (quad << 2);
#pragma unroll
                for (int r = 0; r < 4; ++r) {
                    float vv = acc[mi][ni][r] + bv;
                    if (relu) vv = fmaxf(vv, 0.f);
                    vv *= sc;
                    C[(size_t)(row0 + r) * N + col] = f2b(vv);
                }
            }
        }
    }
}

// ---------------------------------------------------------------------------
// Flash attention v10: MFMA-ones l row-sum + cvt_pk bf16 pack + T14 staging.
// 8 waves x 16 q-rows (512 thr). K double-buffered in LDS (async prefetch),
// V(t+1) reg-staged under compute. l[q] accumulated on the MATRIX pipe:
// l4 = mfma(pf, ones, l4) -> l4[r] = l[quad*4+r] at every lane, no shuffles.
// grid (S/128, B*H), 512 thr.  T1 swizzle: whole heads per XCD.
// ---------------------------------------------------------------------------
__global__ __launch_bounds__(512) void attn_v10(
    const u16* __restrict__ Q, int qs, const u16* __restrict__ Kp, int ks,
    const u16* __restrict__ Vt, u16* __restrict__ O, int os, int Sk)
{
    __shared__ __align__(16) u16 Kl[2][128 * 64]; // [sk][hd]  32 KB dbuf
    __shared__ __align__(16) u16 Vtl[64 * 128];   // [hd][sk]  16 KB
    __shared__ __align__(16) u16 Pl[8][16 * LDP]; //           18 KB

    const int tid  = threadIdx.x;
    const int wave = tid >> 6, lane = tid & 63;
    const int quad = lane >> 4, tl = lane & 15;
    // T1: XCD-aware bijective remap (contiguous heads per XCD)
    const int nwg  = gridDim.x * gridDim.y;
    const int wgid = xcd_swz(blockIdx.y * gridDim.x + blockIdx.x, nwg);
    const int bx   = wgid % gridDim.x, by = wgid / gridDim.x;
    const int b = by >> 4, h = by & 15;
    const int srow = lane >> 3;
    const int scolK = (((lane & 7) ^ srow) << 3);
    const int vri = lane >> 4, vj = lane & 15;   // Vt staging roles

    const u16* qb  = Q  + (size_t)(b * 2048) * qs + h * 64;
    const u16* kb  = Kp + (size_t)(b * 2048) * ks + h * 64;
    const u16* vtb = Vt + (size_t)by * 64 * 2048;
    u16*       ob  = O  + (size_t)(b * 2048) * os + h * 64;
    const int qr0 = bx * 128 + wave * 16;        // 16 q-rows per wave

    v8s qf[2];
#pragma unroll
    for (int kk = 0; kk < 2; ++kk)
        qf[kk] = *(const v8s*)&qb[(size_t)(qr0 + tl) * qs + kk * 32 + quad * 8];

    const v4f z4 = {0.f, 0.f, 0.f, 0.f};
    v4f oacc[4] = {z4, z4, z4, z4};
    v4f l4 = z4;                                 // l[q] accumulated via MFMA
    v8s ones;
#pragma unroll
    for (int i = 0; i < 8; ++i) ones[i] = (short)0x3F80;  // bf16 1.0
    u16* Pw = &Pl[wave][0];

    const int pc0 = (quad ^ (tl & 7)) << 3;
    const int pc1 = ((4 + quad) ^ (tl & 7)) << 3;

    // prologue: stage K(0) -> Kl[0], V(0) -> Vtl
#pragma unroll
    for (int i = 0; i < 2; ++i) {
        const int c = wave * 2 + i;
        gload16(&kb[(size_t)(c * 8 + srow) * ks + scolK], &Kl[0][c * 512]);
    }
#pragma unroll
    for (int i = 0; i < 2; ++i) {
        const int c = wave * 2 + i;
        const int vr = c * 4 + vri;
        const int g = (vj & 8) | ((vj & 7) ^ (vr & 7));
        gload16(&vtb[(size_t)vr * 2048 + (g << 3)], &Vtl[c * 512]);
    }
    __syncthreads();

    int cur = 0;
    for (int kt = 0; kt < Sk; kt += 128) {
        const int more = (kt + 128 < Sk) ? 1 : 0;
        v8s vp0, vp1;
        if (more) {
            // reg-load V(t+1) early: latency hides under this iteration's
            // compute; values land in Vtl after barrier#1.
            {
                const int c = wave * 2 + 0;
                const int vr = c * 4 + vri;
                const int g = (vj & 8) | ((vj & 7) ^ (vr & 7));
                vp0 = *(const v8s*)&vtb[(size_t)vr * 2048 + kt + 128 + (g << 3)];
            }
            {
                const int c = wave * 2 + 1;
                const int vr = c * 4 + vri;
                const int g = (vj & 8) | ((vj & 7) ^ (vr & 7));
                vp1 = *(const v8s*)&vtb[(size_t)vr * 2048 + kt + 128 + (g << 3)];
            }
            // issue K(t+1) -> Kl[cur^1]: async, completes under compute.
#pragma unroll
            for (int i = 0; i < 2; ++i) {
                const int c = wave * 2 + i;
                const int row = c * 8 + srow;
                gload16(&kb[(size_t)(kt + 128 + row) * ks + scolK], &Kl[cur ^ 1][c * 512]);
            }
        }
        const u16* Kc = &Kl[cur][0];

#pragma unroll
        for (int hf = 0; hf < 2; ++hf) {
            // S^T = K*Q^T for this 64-sk half (lane: sk=quad*4+r, q=tl)
#pragma unroll
            for (int nt = 0; nt < 4; ++nt) {
                const int krow = ((hf * 4 + nt) * 16 + tl) * 64;
                v8s k0 = *(const v8s*)&Kc[krow + pc0];
                v8s k1 = *(const v8s*)&Kc[krow + pc1];
                v4f a = z4;
                a = __builtin_amdgcn_mfma_f32_16x16x32_bf16(k0, qf[0], a, 0, 0, 0);
                a = __builtin_amdgcn_mfma_f32_16x16x32_bf16(k1, qf[1], a, 0, 0, 0);
                // bare v_exp_f32: scores pre-scaled by 0.125*log2e, bounded.
                float p0 = __builtin_amdgcn_exp2f(a[0]);
                float p1 = __builtin_amdgcn_exp2f(a[1]);
                float p2 = __builtin_amdgcn_exp2f(a[2]);
                float p3 = __builtin_amdgcn_exp2f(a[3]);
                // T12: single-inst f32x2 -> bf16x2 pack (RNE)
                u32 pk0, pk1;
                asm("v_cvt_pk_bf16_f32 %0, %1, %2" : "=v"(pk0) : "v"(p0), "v"(p1));
                asm("v_cvt_pk_bf16_f32 %0, %1, %2" : "=v"(pk1) : "v"(p2), "v"(p3));
                uint2 pk; pk.x = pk0; pk.y = pk1;
                // P[q][sk]: row = tl, cols nt*16+quad*4 .. +3
                *(uint2*)&Pw[tl * LDP + nt * 16 + quad * 4] = pk;
            }
            asm volatile("" ::: "memory");   // same-wave DS ordering fence

            v8s pf0 = *(const v8s*)&Pw[tl * LDP + quad * 8];
            v8s pf1 = *(const v8s*)&Pw[tl * LDP + 32 + quad * 8];
            const int pv0 = ((hf * 8) | (quad ^ (tl & 7))) << 3;
            const int pv1 = ((hf * 8) | ((4 + quad) ^ (tl & 7))) << 3;
            // T5: pure-MFMA cluster — hint scheduler to keep matrix pipe fed
            __builtin_amdgcn_s_setprio(1);
            // l row-sum on the matrix pipe: B = ones (layout-independent)
            l4 = __builtin_amdgcn_mfma_f32_16x16x32_bf16(pf0, ones, l4, 0, 0, 0);
            l4 = __builtin_amdgcn_mfma_f32_16x16x32_bf16(pf1, ones, l4, 0, 0, 0);
#pragma unroll
            for (int d = 0; d < 4; ++d) {
                const int vbase = (d * 16 + tl) * 128;
                v8s v0 = *(const v8s*)&Vtl[vbase + pv0];
                v8s v1 = *(const v8s*)&Vtl[vbase + pv1];
                oacc[d] = __builtin_amdgcn_mfma_f32_16x16x32_bf16(pf0, v0, oacc[d], 0, 0, 0);
                oacc[d] = __builtin_amdgcn_mfma_f32_16x16x32_bf16(pf1, v1, oacc[d], 0, 0, 0);
            }
            __builtin_amdgcn_s_setprio(0);
            asm volatile("" ::: "memory");   // P region reused next half
        }

        __syncthreads();   // all waves done reading Vtl; prefetches retired
        if (more) {
            // write V(t+1) into Vtl at the gload-linear offsets (same layout)
            *(v8s*)&Vtl[(wave * 2 + 0) * 512 + lane * 8] = vp0;
            *(v8s*)&Vtl[(wave * 2 + 1) * 512 + lane * 8] = vp1;
        }
        __syncthreads();   // Vtl(t+1) visible to all waves
        cur ^= 1;
    }

    // l4[r] = l[q = quad*4 + r] (D-layout row = quad*4+reg, same for all tl)
#pragma unroll
    for (int r = 0; r < 4; ++r) {
        float inv = 1.0f / l4[r];
#pragma unroll
        for (int d = 0; d < 4; ++d)
            ob[(size_t)(qr0 + quad * 4 + r) * os + d * 16 + tl] =
                f2b(oacc[d][r] * inv);
    }
}

// ---------------------------------------------------------------------------
// out = LayerNorm(x + h) * g + b   over D=1024. grid 4096, 256 thr.
// ---------------------------------------------------------------------------
template <int XF32, int OF32>
__global__ __launch_bounds__(256) void add_ln(
    const void* __restrict__ Xv, const u16* __restrict__ Hh,
    const float* __restrict__ G, const float* __restrict__ Bb,
    void* __restrict__ Outv)
{
    const int row = blockIdx.x, t = threadIdx.x;
    float v0, v1, v2, v3;
    {
        ushort4 hv = *(const ushort4*)&Hh[(size_t)row * 1024 + t * 4];
        if (XF32) {
            const float* xr = (const float*)Xv + (size_t)row * 1024;
            float4 xv = *(const float4*)&xr[t * 4];
            v0 = xv.x + b2f(hv.x); v1 = xv.y + b2f(hv.y);
            v2 = xv.z + b2f(hv.z); v3 = xv.w + b2f(hv.w);
        } else {
            const u16* xr = (const u16*)Xv + (size_t)row * 1024;
            ushort4 xv = *(const ushort4*)&xr[t * 4];
            v0 = b2f(xv.x) + b2f(hv.x); v1 = b2f(xv.y) + b2f(hv.y);
            v2 = b2f(xv.z) + b2f(hv.z); v3 = b2f(xv.w) + b2f(hv.w);
        }
    }

    float s1 = v0 + v1 + v2 + v3;
    float s2 = v0 * v0 + v1 * v1 + v2 * v2 + v3 * v3;
#pragma unroll
    for (int o = 1; o < 64; o <<= 1) {
        s1 += __shfl_xor(s1, o);
        s2 += __shfl_xor(s2, o);
    }
    __shared__ float red[8];
    const int wave = t >> 6, lane = t & 63;
    if (lane == 0) { red[wave] = s1; red[4 + wave] = s2; }
    __syncthreads();
    s1 = red[0] + red[1] + red[2] + red[3];
    s2 = red[4] + red[5] + red[6] + red[7];

    const float mu = s1 * (1.f / 1024.f);
    float var = s2 * (1.f / 1024.f) - mu * mu;
    var = fmaxf(var, 0.f);
    const float rs = rsqrtf(var + 1e-5f);

    float4 gv = *(const float4*)&G[t * 4];
    float4 bv = *(const float4*)&Bb[t * 4];
    float o0 = (v0 - mu) * rs * gv.x + bv.x;
    float o1 = (v1 - mu) * rs * gv.y + bv.y;
    float o2 = (v2 - mu) * rs * gv.z + bv.z;
    float o3 = (v3 - mu) * rs * gv.w + bv.w;

    if (OF32) {
        float4 ov = {o0, o1, o2, o3};
        *(float4*)&((float*)Outv)[(size_t)row * 1024 + t * 4] = ov;
    } else {
        ushort4 ov;
        ov.x = f2b(o0); ov.y = f2b(o1); ov.z = f2b(o2); ov.w = f2b(o3);
        *(ushort4*)&((u16*)Outv)[(size_t)row * 1024 + t * 4] = ov;
    }
}

// ---------------------------------------------------------------------------
extern "C" void kernel_launch(void* const* d_in, const int* in_sizes, int n_in,
                              void* d_out, int out_size, void* d_ws, size_t ws_size,
                              hipStream_t stream) {
    const float* x0  = (const float*)d_in[0];
    const float* enc = (const float*)d_in[1];

    char* wsb = (char*)d_ws;
    const size_t MB = 1024u * 1024u;
    // weights region [0,12MB) — dead after projection GEMMs, reused by FFN
    u16*   wt_sa   = (u16*)(wsb);             // [3072][1024]  0-6 MB
    u16*   wt_caq  = (u16*)(wsb + 6  * MB);   // [1024][1024]  6-8 MB
    u16*   wt_cakv = (u16*)(wsb + 8  * MB);   // [2048][1024]  8-12 MB
    float* sab     = (float*)(wsb + 12 * MB);
    float* cakvb   = (float*)(wsb + 12 * MB + 16384);
    char*  arena   = wsb + 12 * MB + 32768;   // 48 MB arena
    // attention phase
    u16* QKV    = (u16*)(arena);            // [4096][3072] 0-24
    u16* hbuf   = (u16*)(arena + 24 * MB);  // [4096][1024] 24-32 (attn outs)
    u16* x0b    = (u16*)(arena + 24 * MB);  // bf16(x0) — dead once attn1 runs
    u16* encb   = (u16*)(arena + 24 * MB);  // bf16(enc) — lives ln1..attn2
    u16* x1     = (u16*)(arena + 32 * MB);  // [4096][1024] 32-40
    u16* Vt     = (u16*)(arena + 40 * MB);  // [32][64][2048] 40-48
    u16* Q2     = (u16*)(arena);            // 0-8   (reuses QKV)
    u16* KV2    = (u16*)(arena + 8  * MB);  // 8-24  (reuses QKV)
    // FFN phase
    u16* x2     = (u16*)(arena);            // 0-8
    u16* wt_fc1 = (u16*)(wsb);              // ws 0-8 (over proj weights)
    u16* wt_fc2 = (u16*)(arena + 8  * MB);  // 8-16  (dead KV2)
    u16* tbuf   = (u16*)(arena + 16 * MB);  // [4096][4096] 16-48
    u16* h3     = (u16*)(wsb);              // ws 0-8 (wt_fc1 dead after fc1)

    const float QSC = 0.125f * LOG2E;

    // fused prep: bias concat + 6 proj-weight transposes + conv(x0)
    prep_all<<<8196, 256, 0, stream>>>(
        (const float*)d_in[3], (const float*)d_in[5], (const float*)d_in[7],
        (const float*)d_in[13], (const float*)d_in[15], sab, cakvb,
        x0, x0b,
        (const float*)d_in[2], (const float*)d_in[4], (const float*)d_in[6],
        (const float*)d_in[10], (const float*)d_in[12], (const float*)d_in[14],
        wt_sa, wt_caq, wt_cakv);

    // --- self-attention block ---
    gemm_bt<128, 128, 1><<<dim3(24, 32), 256, 0, stream>>>(
        x0b, wt_sa, sab, QKV, 4096, 3072, 1024, 0, 1024, QSC, Vt, 2048);
    attn_v10<<<dim3(16, 32), 512, 0, stream>>>(QKV, 3072, QKV + 1024, 3072, Vt, hbuf, 1024, 2048);
    add_ln<1, 0><<<4096, 256, 0, stream>>>(x0, hbuf, (const float*)d_in[8], (const float*)d_in[9], x1);

    // --- cross-attention block ---
    conv_f2b<<<2048, 256, 0, stream>>>(enc, encb);   // encb aliases hbuf/x0b: cannot hoist
    gemm_bt<64, 64, 2><<<dim3(16, 64), 256, 0, stream>>>(
        x1, wt_caq, (const float*)d_in[11], Q2, 4096, 1024, 1024, 0, 1024, QSC, (u16*)nullptr, -1);
    gemm_bt<64, 128, 1><<<dim3(16, 64), 256, 0, stream>>>(
        encb, wt_cakv, cakvb, KV2, 4096, 2048, 1024, 0, 0, 1.0f, Vt, 1024);
    attn_v10<<<dim3(16, 32), 512, 0, stream>>>(Q2, 1024, KV2, 2048, Vt, hbuf, 1024, 2048);
    add_ln<0, 0><<<4096, 256, 0, stream>>>(x1, hbuf, (const float*)d_in[16], (const float*)d_in[17], x2);

    // --- FFN block ---
    prep_fc<<<8192, 256, 0, stream>>>(
        (const float*)d_in[18], (const float*)d_in[20], wt_fc1, wt_fc2);
    gemm_bt<128, 128, 1><<<dim3(32, 32), 256, 0, stream>>>(
        x2, wt_fc1, (const float*)d_in[19], tbuf, 4096, 4096, 1024, 1, 0, 1.0f, (u16*)nullptr, -1);
    gemm_bt<64, 64, 2><<<dim3(16, 64), 256, 0, stream>>>(
        tbuf, wt_fc2, (const float*)d_in[21], h3, 4096, 1024, 4096, 0, 0, 1.0f, (u16*)nullptr, -1);
    add_ln<0, 1><<<4096, 256, 0, stream>>>(x2, h3, (const float*)d_in[22], (const float*)d_in[23], d_out);
}